// Round 2
// baseline (1594.409 us; speedup 1.0000x reference)
//
#include <hip/hip_runtime.h>
#include <math.h>

#define N_NODES 100000
#define N_EDGES 1200000
#define GC 64
#define RBF 32
#define NLAYERS 4
#define NF 92
#define NATOM 100
#define BN_EPS 1e-5f
#define AGG_BLOCKS 2048

typedef _Float16 h2 __attribute__((ext_vector_type(2)));
union U32H2 { unsigned int u; h2 h; };

static __device__ __forceinline__ int rfl(int v) { return __builtin_amdgcn_readfirstlane(v); }

static __device__ __forceinline__ float dot2(unsigned int e, h2 w, float acc) {
    U32H2 c; c.u = e;
#if __has_builtin(__builtin_amdgcn_fdot2)
    return __builtin_amdgcn_fdot2(c.h, w, acc, false);
#else
    return fmaf((float)c.h.x, (float)w.x, fmaf((float)c.h.y, (float)w.y, acc));
#endif
}

// ---------- K1: degree histogram ----------
__global__ __launch_bounds__(256) void deg_kernel(
    const int* __restrict__ ei, int* __restrict__ deg)
{
    int e = blockIdx.x * 256 + threadIdx.x;
    if (e >= N_EDGES) return;
    int d = ei[N_EDGES + e];
    atomicAdd(&deg[d], 1);
}

// ---------- scan: block sums ----------
__global__ __launch_bounds__(256) void scan_a_kernel(const int* __restrict__ deg, int* __restrict__ bsums)
{
    __shared__ int sm[256];
    int tid = threadIdx.x;
    int i = blockIdx.x * 256 + tid;
    int v = (i < N_NODES) ? deg[i] : 0;
    sm[tid] = v;
    __syncthreads();
    for (int s = 128; s > 0; s >>= 1) {
        if (tid < s) sm[tid] += sm[tid + s];
        __syncthreads();
    }
    if (tid == 0) bsums[blockIdx.x] = sm[0];
}

// ---------- scan: scan block sums (single block, 512 threads >= 391 blocks) ----------
__global__ __launch_bounds__(512) void scan_b_kernel(const int* __restrict__ bsums, int* __restrict__ boffs)
{
    __shared__ int sm[512];
    int tid = threadIdx.x;
    int v = (tid < 391) ? bsums[tid] : 0;
    sm[tid] = v;
    __syncthreads();
    for (int off = 1; off < 512; off <<= 1) {
        int t = (tid >= off) ? sm[tid - off] : 0;
        __syncthreads();
        sm[tid] += t;
        __syncthreads();
    }
    boffs[tid] = (tid == 0) ? 0 : sm[tid - 1];
}

// ---------- scan: row_start + inv_deg ----------
__global__ __launch_bounds__(256) void scan_c_kernel(
    const int* __restrict__ deg, const int* __restrict__ boffs,
    int* __restrict__ row_st, float* __restrict__ inv_deg)
{
    __shared__ int sm[256];
    int tid = threadIdx.x;
    int i = blockIdx.x * 256 + tid;
    int v = (i < N_NODES) ? deg[i] : 0;
    sm[tid] = v;
    __syncthreads();
    for (int off = 1; off < 256; off <<= 1) {
        int t = (tid >= off) ? sm[tid - off] : 0;
        __syncthreads();
        sm[tid] += t;
        __syncthreads();
    }
    if (i <= N_NODES) row_st[i] = boffs[blockIdx.x] + sm[tid] - v;  // exclusive
    if (i < N_NODES) inv_deg[i] = (v > 0) ? (1.0f / (float)v) : 0.0f;
}

// ---------- K2: scatter edges into CSR order + fused RBF (fp16) ----------
__global__ __launch_bounds__(256) void scatter_rbf_kernel(
    const int* __restrict__ ei, const float* __restrict__ pos,
    const int* __restrict__ row_st, int* __restrict__ cursor,
    const float* __restrict__ means, const float* __restrict__ betas,
    int* __restrict__ csr_src, unsigned int* __restrict__ ea)
{
    int e = blockIdx.x * 256 + threadIdx.x;
    if (e >= N_EDGES) return;
    int s = ei[e];
    int d = ei[N_EDGES + e];
    float dx = pos[s * 3 + 0] - pos[d * 3 + 0];
    float dy = pos[s * 3 + 1] - pos[d * 3 + 1];
    float dz = pos[s * 3 + 2] - pos[d * 3 + 2];
    float dist = sqrtf(dx * dx + dy * dy + dz * dz + 1e-12f);

    int p = atomicAdd(&cursor[d], 1);
    int idx = row_st[d] + p;
    csr_src[idx] = s;

    float cut = 0.0f;
    if (dist < 5.0f) cut = 0.5f * (__cosf(dist * 0.6283185307179586f) + 1.0f);
    float ex = __expf(-dist);
    union { _Float16 h[32]; uint4 u[4]; } pk;
#pragma unroll
    for (int k = 0; k < 32; k++) {
        float v = ex - means[k];
        pk.h[k] = (_Float16)(cut * __expf(-betas[k] * v * v));
    }
    uint4* op = (uint4*)(ea + (size_t)idx * 16);
    op[0] = pk.u[0];
    op[1] = pk.u[1];
    op[2] = pk.u[2];
    op[3] = pk.u[3];
}

// ---------- K4a: per-atom-type pre-layer table ----------
__global__ __launch_bounds__(64) void atom_table_kernel(
    const float* __restrict__ emb, const float* __restrict__ pre_W,
    const float* __restrict__ pre_b, float* __restrict__ T)
{
    int a = blockIdx.x;
    int c = threadIdx.x;
    float acc = pre_b[c];
    for (int k = 0; k < NF; k++) acc = fmaf(emb[a * NF + k], pre_W[k * GC + c], acc);
    T[a * GC + c] = fmaxf(acc, 0.0f);
}

// ---------- K4b: broadcast table to nodes ----------
__global__ __launch_bounds__(256) void xinit_kernel(
    const int* __restrict__ atom_types, const float* __restrict__ T, float* __restrict__ x)
{
    int i = blockIdx.x * 256 + threadIdx.x;  // i < N*16 (float4 granules)
    int n = i >> 4;
    int a = atom_types[n];
    ((float4*)x)[i] = ((const float4*)T)[a * 16 + (i & 15)];
}

// ---------- K5: four per-node projections -> fp16 P ----------
__global__ __launch_bounds__(256) void proj_kernel(
    const float* __restrict__ x, const float* __restrict__ Wf, const float* __restrict__ Ws,
    const float* __restrict__ bfv, const float* __restrict__ bsv, _Float16* __restrict__ P)
{
    const int lane = threadIdx.x & 63;
    const int m = rfl(threadIdx.x >> 6);  // 0..3: fd, fs, sd, ss
    const int nb = blockIdx.x * 16;

    const float* Wsel;
    float bias = 0.0f;
    if (m == 0) { Wsel = Wf; bias = bfv[lane]; }
    else if (m == 1) { Wsel = Wf + 64 * GC; }
    else if (m == 2) { Wsel = Ws; bias = bsv[lane]; }
    else { Wsel = Ws + 64 * GC; }

    float w[64];
#pragma unroll
    for (int k = 0; k < 64; k++) w[k] = Wsel[k * GC + lane];

    _Float16* out = P + (size_t)m * N_NODES * GC;
    for (int n = 0; n < 16; n++) {
        const float* xp = x + (size_t)(nb + n) * GC;
        float a0 = bias, a1 = 0.f, a2 = 0.f, a3 = 0.f;
#pragma unroll
        for (int k = 0; k < 64; k += 4) {
            a0 = fmaf(xp[k + 0], w[k + 0], a0);
            a1 = fmaf(xp[k + 1], w[k + 1], a1);
            a2 = fmaf(xp[k + 2], w[k + 2], a2);
            a3 = fmaf(xp[k + 3], w[k + 3], a3);
        }
        out[(size_t)(nb + n) * GC + lane] = (_Float16)((a0 + a1) + (a2 + a3));
    }
}

// ---------- K6: node-centric aggregate + residual (in-place x) + BN stats ----------
__global__ __launch_bounds__(256) void agg_kernel(
    const _Float16* __restrict__ P, const unsigned int* __restrict__ ea,
    const int* __restrict__ csr_src, const int* __restrict__ row_st,
    const float* __restrict__ inv_deg, float* __restrict__ x,
    const float* __restrict__ WfE, const float* __restrict__ WsE,
    float* __restrict__ stats)
{
    const int lane = threadIdx.x & 63;
    const int wid = rfl(threadIdx.x >> 6);

    h2 wf2[16], ws2[16];
#pragma unroll
    for (int k2 = 0; k2 < 16; k2++) {
        h2 a, b;
        a.x = (_Float16)WfE[(2 * k2) * GC + lane];
        a.y = (_Float16)WfE[(2 * k2 + 1) * GC + lane];
        b.x = (_Float16)WsE[(2 * k2) * GC + lane];
        b.y = (_Float16)WsE[(2 * k2 + 1) * GC + lane];
        wf2[k2] = a;
        ws2[k2] = b;
    }
    const size_t NC = (size_t)N_NODES * GC;
    const _Float16* Pfd = P;
    const _Float16* Pfs = P + NC;
    const _Float16* Psd = P + 2 * NC;
    const _Float16* Pss = P + 3 * NC;

    float s1 = 0.0f, s2 = 0.0f;
    int wgid = blockIdx.x * 4 + wid;
    for (int n = wgid; n < N_NODES; n += AGG_BLOCKS * 4) {
        int row = row_st[n];
        int end = row_st[n + 1];
        float pfd = (float)Pfd[(size_t)n * GC + lane];
        float psd = (float)Psd[(size_t)n * GC + lane];
        float acc = 0.0f;
        for (int j = row; j < end; j++) {
            int s = rfl(csr_src[j]);
            const uint4* eap = (const uint4*)(ea + (size_t)j * 16);
            uint4 q0 = eap[0], q1 = eap[1], q2 = eap[2], q3 = eap[3];
            float pfs = (float)Pfs[(size_t)s * GC + lane];
            float pss = (float)Pss[(size_t)s * GC + lane];
            float af0 = pfd + pfs, af1 = 0.0f;
            float as0 = psd + pss, as1 = 0.0f;
            af0 = dot2(q0.x, wf2[0], af0);  af1 = dot2(q0.y, wf2[1], af1);
            af0 = dot2(q0.z, wf2[2], af0);  af1 = dot2(q0.w, wf2[3], af1);
            af0 = dot2(q1.x, wf2[4], af0);  af1 = dot2(q1.y, wf2[5], af1);
            af0 = dot2(q1.z, wf2[6], af0);  af1 = dot2(q1.w, wf2[7], af1);
            af0 = dot2(q2.x, wf2[8], af0);  af1 = dot2(q2.y, wf2[9], af1);
            af0 = dot2(q2.z, wf2[10], af0); af1 = dot2(q2.w, wf2[11], af1);
            af0 = dot2(q3.x, wf2[12], af0); af1 = dot2(q3.y, wf2[13], af1);
            af0 = dot2(q3.z, wf2[14], af0); af1 = dot2(q3.w, wf2[15], af1);
            as0 = dot2(q0.x, ws2[0], as0);  as1 = dot2(q0.y, ws2[1], as1);
            as0 = dot2(q0.z, ws2[2], as0);  as1 = dot2(q0.w, ws2[3], as1);
            as0 = dot2(q1.x, ws2[4], as0);  as1 = dot2(q1.y, ws2[5], as1);
            as0 = dot2(q1.z, ws2[6], as0);  as1 = dot2(q1.w, ws2[7], as1);
            as0 = dot2(q2.x, ws2[8], as0);  as1 = dot2(q2.y, ws2[9], as1);
            as0 = dot2(q2.z, ws2[10], as0); as1 = dot2(q2.w, ws2[11], as1);
            as0 = dot2(q3.x, ws2[12], as0); as1 = dot2(q3.y, ws2[13], as1);
            as0 = dot2(q3.z, ws2[14], as0); as1 = dot2(q3.w, ws2[15], as1);
            float af = af0 + af1, as = as0 + as1;
            float sg = __builtin_amdgcn_rcpf(1.0f + __expf(-af));
            float sp = fmaxf(as, 0.0f) + __logf(1.0f + __expf(-fabsf(as)));
            acc = fmaf(sg, sp, acc);
        }
        float xn = fmaf(acc, inv_deg[n], x[(size_t)n * GC + lane]);
        x[(size_t)n * GC + lane] = xn;
        s1 += xn;
        s2 = fmaf(xn, xn, s2);
    }

    __shared__ float rs1[4][64];
    __shared__ float rs2[4][64];
    rs1[wid][lane] = s1;
    rs2[wid][lane] = s2;
    __syncthreads();
    if (threadIdx.x < 64) {
        float t = rs1[0][lane] + rs1[1][lane] + rs1[2][lane] + rs1[3][lane];
        atomicAdd(&stats[lane], t);
    } else if (threadIdx.x < 128) {
        int c = threadIdx.x & 63;
        float t = rs2[0][c] + rs2[1][c] + rs2[2][c] + rs2[3][c];
        atomicAdd(&stats[64 + c], t);
    }
}

// ---------- K7: batchnorm apply (in place, or to d_out on last layer) ----------
__global__ __launch_bounds__(256) void bn_kernel(
    const float* __restrict__ xn, const float* __restrict__ stats,
    const float* __restrict__ gamma, const float* __restrict__ beta,
    float* __restrict__ out)
{
    int i = blockIdx.x * 256 + threadIdx.x;  // i < N*16
    int c4 = (i & 15) * 4;
    float4 v = ((const float4*)xn)[i];
    float vv[4] = {v.x, v.y, v.z, v.w};
    float o[4];
    const float invN = 1.0f / (float)N_NODES;
#pragma unroll
    for (int t = 0; t < 4; t++) {
        int c = c4 + t;
        float mu = stats[c] * invN;
        float var = stats[64 + c] * invN - mu * mu;
        float sc = gamma[c] * rsqrtf(var + BN_EPS);
        o[t] = (vv[t] - mu) * sc + beta[c];
    }
    ((float4*)out)[i] = make_float4(o[0], o[1], o[2], o[3]);
}

extern "C" void kernel_launch(void* const* d_in, const int* in_sizes, int n_in,
                              void* d_out, int out_size, void* d_ws, size_t ws_size,
                              hipStream_t stream)
{
    const int* atom_types = (const int*)d_in[0];
    const float* pos = (const float*)d_in[1];
    const int* edge_index = (const int*)d_in[2];
    const float* emb = (const float*)d_in[3];
    const float* pre_W = (const float*)d_in[4];
    const float* pre_b = (const float*)d_in[5];
    const float* Wf = (const float*)d_in[6];
    const float* bf = (const float*)d_in[7];
    const float* Ws = (const float*)d_in[8];
    const float* bs = (const float*)d_in[9];
    const float* gamma = (const float*)d_in[10];
    const float* beta = (const float*)d_in[11];
    const float* means = (const float*)d_in[12];
    const float* betas = (const float*)d_in[13];

    char* base = (char*)d_ws;
    char* p = base;
    auto alloc = [&](size_t bytes) -> char* {
        char* r = p;
        p += (bytes + 255) & ~(size_t)255;
        return r;
    };
    unsigned int* ea = (unsigned int*)alloc((size_t)N_EDGES * RBF * 2);   // 76.8 MB fp16
    _Float16* P = (_Float16*)alloc((size_t)4 * N_NODES * GC * 2);         // 51.2 MB fp16
    float* x = (float*)alloc((size_t)N_NODES * GC * 4);                   // 25.6 MB
    int* csr_src = (int*)alloc((size_t)N_EDGES * 4);                      // 4.8 MB
    int* row_st = (int*)alloc((size_t)(N_NODES + 1) * 4);
    float* inv_deg = (float*)alloc((size_t)N_NODES * 4);
    float* T = (float*)alloc((size_t)NATOM * GC * 4);
    int* bsums = (int*)alloc(512 * 4);
    int* boffs = (int*)alloc(512 * 4);
    char* zr = alloc((size_t)(2 * N_NODES + 128 * NLAYERS) * 4);
    int* deg = (int*)zr;
    int* cursor = deg + N_NODES;
    float* stats = (float*)(cursor + N_NODES);

    // Guard: if the workspace is too small, bail out (leaves poison in d_out ->
    // clean absmax failure instead of a GPU memory fault).
    if ((size_t)(p - base) > ws_size) return;

    hipMemsetAsync(zr, 0, (size_t)(2 * N_NODES + 128 * NLAYERS) * 4, stream);

    const int EG = (N_EDGES + 255) / 256;
    deg_kernel<<<EG, 256, 0, stream>>>(edge_index, deg);
    scan_a_kernel<<<391, 256, 0, stream>>>(deg, bsums);
    scan_b_kernel<<<1, 512, 0, stream>>>(bsums, boffs);
    scan_c_kernel<<<391, 256, 0, stream>>>(deg, boffs, row_st, inv_deg);
    scatter_rbf_kernel<<<EG, 256, 0, stream>>>(edge_index, pos, row_st, cursor,
                                               means, betas, csr_src, ea);
    atom_table_kernel<<<NATOM, 64, 0, stream>>>(emb, pre_W, pre_b, T);
    xinit_kernel<<<N_NODES * 16 / 256, 256, 0, stream>>>(atom_types, T, x);

    for (int l = 0; l < NLAYERS; l++) {
        const float* Wfl = Wf + (size_t)l * 160 * GC;
        const float* Wsl = Ws + (size_t)l * 160 * GC;
        proj_kernel<<<N_NODES / 16, 256, 0, stream>>>(x, Wfl, Wsl, bf + l * GC, bs + l * GC, P);
        agg_kernel<<<AGG_BLOCKS, 256, 0, stream>>>(P, ea, csr_src, row_st, inv_deg, x,
                                                   Wfl + 128 * GC, Wsl + 128 * GC,
                                                   stats + l * 128);
        bn_kernel<<<N_NODES * 16 / 256, 256, 0, stream>>>(x, stats + l * 128,
                                                          gamma + l * GC, beta + l * GC,
                                                          (l == NLAYERS - 1) ? (float*)d_out : x);
    }
}